// Round 15
// baseline (374.022 us; speedup 1.0000x reference)
//
#include <hip/hip_runtime.h>

#define NEG_SLOPE 0.2f
#define CAP1 224
#define CAP2 224
#define CAPB 5120    // per-bin capacity (bin mean ~4224, sd ~65 -> +13 sd)
#define EPB  16384   // edges per binscat block
#define OVFCAP 65536

typedef short bf16x8 __attribute__((ext_vector_type(8)));
typedef float f32x4  __attribute__((ext_vector_type(4)));
typedef float f32x2  __attribute__((ext_vector_type(2)));

static __device__ __forceinline__ float u16f(unsigned short u){
  union { unsigned int i; float f; } v; v.i = ((unsigned int)u) << 16; return v.f;
}
static __device__ __forceinline__ unsigned short f2u16(float f){
  union { float f; unsigned int i; } v; v.f = f;
  unsigned int r = (v.i + 0x7FFFu + ((v.i >> 16) & 1u)) >> 16;
  return (unsigned short)r;
}
static __device__ __forceinline__ unsigned char f2fp8(float f){
  int w = __builtin_amdgcn_cvt_pk_fp8_f32(f, f, 0, false);
  return (unsigned char)(w & 0xFF);
}
static __device__ __forceinline__ float fp82f(unsigned char b){
  f32x2 d = __builtin_amdgcn_cvt_pk_f32_fp8((int)b, false);
  return d[0];
}
static __device__ __forceinline__ float wsum(float v){
  #pragma unroll
  for (int o = 32; o > 0; o >>= 1) v += __shfl_xor(v, o, 64);
  return v;
}
static __device__ __forceinline__ float qsum(float v){
  #pragma unroll
  for (int o = 1; o < 16; o <<= 1) v += __shfl_xor(v, o, 64);
  return v;
}
static __device__ __forceinline__ float lrelu(float e){
  return e >= 0.f ? e : NEG_SLOPE * e;
}

__global__ __launch_bounds__(256) void k_zero(int* __restrict__ p, int nwords){
  int i = blockIdx.x * 256 + threadIdx.x;
  if (i < nwords) p[i] = 0;
}

// ---- fused prep: cvt x->bf16, pack W1, pack W2 (grid-sectioned)
__global__ __launch_bounds__(256) void k_prep(const float* __restrict__ x,
                                              unsigned short* __restrict__ xb, int n4,
                                              const float* __restrict__ W1,
                                              unsigned short* __restrict__ B1p,
                                              const float* __restrict__ W2,
                                              unsigned short* __restrict__ B2p,
                                              int cvtBlocks){
  int b = blockIdx.x, t = threadIdx.x;
  if (b < cvtBlocks){
    int i = b * 256 + t;
    if (i >= n4) return;
    float4 f = ((const float4*)x)[i];
    ushort4 u;
    u.x = f2u16(f.x); u.y = f2u16(f.y); u.z = f2u16(f.z); u.w = f2u16(f.w);
    ((ushort4*)xb)[i] = u;
  } else if (b < cvtBlocks + 128){
    int idx = (b - cvtBlocks) * 256 + t;   // [0, 32768)
    int j = idx & 7, lane = (idx >> 3) & 63, nt = (idx >> 9) & 15, kc = idx >> 13;
    int k = kc*32 + (lane >> 4)*8 + j;
    int n = nt*16 + (lane & 15);
    B1p[idx] = f2u16(W1[k*256 + n]);
  } else {
    int idx = (b - cvtBlocks - 128) * 256 + t;  // [0, 16384)
    int j = idx & 7, lane = (idx >> 3) & 63, nt = (idx >> 9) & 3, kc = idx >> 11;
    int k = kc*32 + (lane >> 4)*8 + j;
    int n = nt*16 + (lane & 15);
    B2p[idx] = f2u16(W2[k*64 + n]);
  }
}

// ---- layer1 GEMM via MFMA: xw1 = x @ W1 (fp8 out), alpha vectors fp32 [N,4]
// Epilogue stages fp8 bytes through LDS -> coalesced dwordx4 stores.
__global__ __launch_bounds__(256) void k_gemm1m(
    const unsigned short* __restrict__ xb, const bf16x8* __restrict__ B1p,
    const float* __restrict__ asrc, const float* __restrict__ adst,
    unsigned char* __restrict__ xw1, float* __restrict__ oas, float* __restrict__ oad,
    int N)
{
  __shared__ unsigned short xs[64][136];
  int t = threadIdx.x;
  int m0 = blockIdx.x * 64;
  #pragma unroll
  for (int i = 0; i < 4; ++i){
    int flat = t + i*256;
    int r = flat >> 4, c8 = flat & 15;
    uint4 v = make_uint4(0,0,0,0);
    if (m0 + r < N) v = *(const uint4*)(xb + (size_t)(m0 + r)*128 + c8*8);
    *(uint4*)&xs[r][c8*8] = v;
  }
  __syncthreads();
  int w = t >> 6, l = t & 63;
  int quad = l >> 4, ml = l & 15;

  f32x4 acc[16];
  #pragma unroll
  for (int i = 0; i < 16; ++i){ acc[i][0]=0.f; acc[i][1]=0.f; acc[i][2]=0.f; acc[i][3]=0.f; }

  #pragma unroll
  for (int kc = 0; kc < 4; ++kc){
    bf16x8 a = *(const bf16x8*)&xs[w*16 + ml][kc*32 + quad*8];
    #pragma unroll
    for (int nt = 0; nt < 16; ++nt){
      bf16x8 b = B1p[(kc*16 + nt)*64 + l];
      acc[nt] = __builtin_amdgcn_mfma_f32_16x16x32_bf16(a, b, acc[nt], 0, 0, 0);
    }
  }

  float as_h[4][4], ad_h[4][4];
  #pragma unroll
  for (int h = 0; h < 4; ++h)
    #pragma unroll
    for (int r = 0; r < 4; ++r){ as_h[h][r] = 0.f; ad_h[h][r] = 0.f; }
  #pragma unroll
  for (int nt = 0; nt < 16; ++nt){
    float vs = asrc[nt*16 + ml], vd = adst[nt*16 + ml];
    int h = nt >> 2;
    #pragma unroll
    for (int r = 0; r < 4; ++r){
      as_h[h][r] += acc[nt][r] * vs;
      ad_h[h][r] += acc[nt][r] * vd;
    }
  }
  #pragma unroll
  for (int h = 0; h < 4; ++h)
    #pragma unroll
    for (int r = 0; r < 4; ++r){ as_h[h][r] = qsum(as_h[h][r]); ad_h[h][r] = qsum(ad_h[h][r]); }

  int baserow = m0 + w*16 + quad*4;
  if (ml == 0){
    #pragma unroll
    for (int r = 0; r < 4; ++r){
      int node = baserow + r;
      if (node < N){
        *(float4*)(oas + (size_t)node*4) = make_float4(as_h[0][r], as_h[1][r], as_h[2][r], as_h[3][r]);
        *(float4*)(oad + (size_t)node*4) = make_float4(ad_h[0][r], ad_h[1][r], ad_h[2][r], ad_h[3][r]);
      }
    }
  }

  // fp8 epilogue via LDS staging
  __syncthreads();
  unsigned char* sb = (unsigned char*)&xs[0][0]; // [64][256] bytes
  #pragma unroll
  for (int r = 0; r < 4; ++r){
    int lrow = w*16 + quad*4 + r;
    #pragma unroll
    for (int nt = 0; nt < 16; ++nt)
      sb[lrow*256 + nt*16 + ml] = f2fp8(acc[nt][r]);
  }
  __syncthreads();
  #pragma unroll
  for (int i = 0; i < 4; ++i){
    int flat = t + i*256;
    int row = flat >> 4, c16 = flat & 15;
    int node = m0 + row;
    if (node < N)
      *(uint4*)(xw1 + (size_t)node*256 + c16*16) = *(const uint4*)(sb + row*256 + c16*16);
  }
}

// ---- layer2 GEMM via MFMA: xw2 = h1 @ W2 (fp8 out), alpha scalars
__global__ __launch_bounds__(256) void k_gemm2m(
    const unsigned short* __restrict__ h1, const bf16x8* __restrict__ B2p,
    const float* __restrict__ asrc, const float* __restrict__ adst,
    unsigned char* __restrict__ xw2, float* __restrict__ oas, float* __restrict__ oad,
    int N)
{
  __shared__ unsigned short ys[64][264];
  int t = threadIdx.x;
  int m0 = blockIdx.x * 64;
  #pragma unroll
  for (int i = 0; i < 8; ++i){
    int flat = t + i*256;
    int r = flat >> 5, c8 = flat & 31;
    uint4 v = make_uint4(0,0,0,0);
    if (m0 + r < N) v = *(const uint4*)(h1 + (size_t)(m0 + r)*256 + c8*8);
    *(uint4*)&ys[r][c8*8] = v;
  }
  __syncthreads();
  int w = t >> 6, l = t & 63;
  int quad = l >> 4, ml = l & 15;

  f32x4 acc[4];
  #pragma unroll
  for (int i = 0; i < 4; ++i){ acc[i][0]=0.f; acc[i][1]=0.f; acc[i][2]=0.f; acc[i][3]=0.f; }

  #pragma unroll
  for (int kc = 0; kc < 8; ++kc){
    bf16x8 a = *(const bf16x8*)&ys[w*16 + ml][kc*32 + quad*8];
    #pragma unroll
    for (int nt = 0; nt < 4; ++nt){
      bf16x8 b = B2p[(kc*4 + nt)*64 + l];
      acc[nt] = __builtin_amdgcn_mfma_f32_16x16x32_bf16(a, b, acc[nt], 0, 0, 0);
    }
  }

  float as_p[4] = {0,0,0,0}, ad_p[4] = {0,0,0,0};
  #pragma unroll
  for (int nt = 0; nt < 4; ++nt){
    float vs = asrc[nt*16 + ml], vd = adst[nt*16 + ml];
    #pragma unroll
    for (int r = 0; r < 4; ++r){
      as_p[r] += acc[nt][r] * vs;
      ad_p[r] += acc[nt][r] * vd;
    }
  }
  #pragma unroll
  for (int r = 0; r < 4; ++r){ as_p[r] = qsum(as_p[r]); ad_p[r] = qsum(ad_p[r]); }

  int baserow = m0 + w*16 + quad*4;
  if (ml == 0){
    #pragma unroll
    for (int r = 0; r < 4; ++r){
      int node = baserow + r;
      if (node < N){ oas[node] = as_p[r]; oad[node] = ad_p[r]; }
    }
  }

  // fp8 epilogue via LDS staging
  __syncthreads();
  unsigned char* sb = (unsigned char*)&ys[0][0]; // [64][64] bytes
  #pragma unroll
  for (int r = 0; r < 4; ++r){
    int lrow = w*16 + quad*4 + r;
    #pragma unroll
    for (int nt = 0; nt < 4; ++nt)
      sb[lrow*64 + nt*16 + ml] = f2fp8(acc[nt][r]);
  }
  __syncthreads();
  {
    int flat = t;
    int row = flat >> 2, c16 = flat & 3;
    int node = m0 + row;
    if (node < N)
      *(uint4*)(xw2 + (size_t)node*64 + c16*16) = *(const uint4*)(sb + row*64 + c16*16);
  }
}

// ---- scans over per-node counts -> CSR row offsets
__global__ __launch_bounds__(256) void k_scan1(const int* __restrict__ count,
                                               int* __restrict__ ro, int* __restrict__ bsum, int N){
  __shared__ int sd[256];
  int t = threadIdx.x, b = blockIdx.x, i = b*256 + t;
  int v = (i < N) ? count[i] : 0;
  sd[t] = v; __syncthreads();
  for (int o = 1; o < 256; o <<= 1){
    int x = (t >= o) ? sd[t - o] : 0;
    __syncthreads();
    sd[t] += x;
    __syncthreads();
  }
  if (i < N) ro[i] = sd[t] - v;  // exclusive
  if (t == 255) bsum[b] = sd[255];
}

__global__ __launch_bounds__(256) void k_scan2(int* __restrict__ bsum, int nb){
  __shared__ int sd[256];
  int t = threadIdx.x;
  int v = (t < nb) ? bsum[t] : 0;
  sd[t] = v; __syncthreads();
  for (int o = 1; o < 256; o <<= 1){
    int x = (t >= o) ? sd[t - o] : 0;
    __syncthreads();
    sd[t] += x;
    __syncthreads();
  }
  if (t < nb) bsum[t] = sd[t] - v;  // exclusive
}

__global__ __launch_bounds__(256) void k_scan3(int* __restrict__ ro,
                                               const int* __restrict__ bsum, int N, int ET){
  int b = blockIdx.x, t = threadIdx.x, i = b*256 + t;
  if (i < N) ro[i] += bsum[b];
  if (b == 0 && t == 0) ro[N] = ET;
}

// ---- Pass B: block-chunked reservation scatter.
__global__ __launch_bounds__(1024) void k_binscat(const int* __restrict__ ei,
                                                  int* __restrict__ bincur,
                                                  int* __restrict__ binbuf,
                                                  int* __restrict__ ovfcnt,
                                                  int2* __restrict__ ovfbuf,
                                                  int E, int ET, int NB){
  __shared__ int lhist[512];
  __shared__ int lbase[512];
  __shared__ int lcur[512];
  int t = threadIdx.x;
  int base = blockIdx.x * EPB;
  for (int i = t; i < 512; i += 1024){ lhist[i] = 0; lcur[i] = 0; }
  __syncthreads();

  int myb[16], mypay[16];
  #pragma unroll
  for (int k = 0; k < 16; ++k){
    int i = base + t + k*1024;
    int b = -1, pay = 0;
    if (i < ET){
      int s, d;
      if (i < E){ s = ei[i]; d = ei[E + i]; }
      else      { s = i - E; d = i - E; }
      b = d >> 7;
      pay = ((d & 127) << 16) | s;
      atomicAdd(&lhist[b], 1);
    }
    myb[k] = b; mypay[k] = pay;
  }
  __syncthreads();

  for (int i = t; i < NB; i += 1024){
    int h = lhist[i];
    if (h > 0) lbase[i] = atomicAdd(&bincur[i * 16], h);
  }
  __syncthreads();

  #pragma unroll
  for (int k = 0; k < 16; ++k){
    int b = myb[k];
    if (b < 0) continue;
    int pos = lbase[b] + atomicAdd(&lcur[b], 1);
    if (pos < CAPB){
      binbuf[(size_t)b * CAPB + pos] = mypay[k];
    } else {
      int d = (b << 7) | (mypay[k] >> 16);
      int s = mypay[k] & 0xFFFF;
      int idx = atomicAdd(ovfcnt, 1);
      if (idx < OVFCAP) ovfbuf[idx] = make_int2(d, s);
    }
  }
}

// ---- per-node counts from binbuf: one block per bin, LDS histogram, coalesced write.
__global__ __launch_bounds__(256) void k_cnt(const int* __restrict__ bincur,
                                             const int* __restrict__ binbuf,
                                             int* __restrict__ count, int N){
  __shared__ int lcnt[128];
  int b = blockIdx.x, t = threadIdx.x;
  int base = b << 7;
  int wn = N - base; if (wn > 128) wn = 128;
  if (wn <= 0) return;
  for (int i = t; i < wn; i += 256) lcnt[i] = 0;
  __syncthreads();
  int total = bincur[b * 16];
  int cnt = total < CAPB ? total : CAPB;
  const int* buf = binbuf + (size_t)b * CAPB;
  for (int i = t; i < cnt; i += 256) atomicAdd(&lcnt[buf[i] >> 16], 1);
  __syncthreads();
  for (int i = t; i < wn; i += 256) count[base + i] = lcnt[i];
}

// ---- count overflow-list entries (normally zero iterations)
__global__ __launch_bounds__(256) void k_cntovf(const int* __restrict__ ovfcnt,
                                                const int2* __restrict__ ovfbuf,
                                                int* __restrict__ count){
  int n = ovfcnt[0]; if (n > OVFCAP) n = OVFCAP;
  for (int i = blockIdx.x*256 + threadIdx.x; i < n; i += gridDim.x*256)
    atomicAdd(&count[ovfbuf[i].x], 1);
}

// ---- scatter overflow-list entries into csr from segment END
__global__ __launch_bounds__(256) void k_ovfscat(const int* __restrict__ ovfcnt,
                                                 const int2* __restrict__ ovfbuf,
                                                 const int* __restrict__ ro,
                                                 int* __restrict__ cursor,
                                                 int* __restrict__ csr){
  int n = ovfcnt[0]; if (n > OVFCAP) n = OVFCAP;
  for (int i = blockIdx.x*256 + threadIdx.x; i < n; i += gridDim.x*256){
    int d = ovfbuf[i].x, s = ovfbuf[i].y;
    int pos = atomicAdd(&cursor[d], 1);
    csr[ro[d + 1] - 1 - pos] = s;
  }
}

// ---- Pass C: one block per bin; rank via LDS atomics, stage in LDS, coalesced csr write
__global__ __launch_bounds__(256) void k_binsort(const int* __restrict__ bincur,
                                                 const int* __restrict__ binbuf,
                                                 const int* __restrict__ ro,
                                                 int* __restrict__ csr, int N){
  __shared__ int rolocal[129];
  __shared__ int lcnt[128];
  __shared__ int stage[CAPB];
  int b = blockIdx.x, t = threadIdx.x;
  int base = b << 7;
  int wn = N - base; if (wn > 128) wn = 128;
  if (wn <= 0) return;
  for (int i = t; i <= wn; i += 256) rolocal[i] = ro[base + i];
  for (int i = t; i < wn; i += 256) lcnt[i] = 0;
  __syncthreads();
  int rostart = rolocal[0];
  int seglen = rolocal[wn] - rostart;
  int total = bincur[b * 16];
  int cnt = total < CAPB ? total : CAPB;
  bool ovf = (seglen > CAPB) || (total > CAPB);
  const int* buf = binbuf + (size_t)b * CAPB;

  if (!ovf){
    for (int i = t; i < cnt; i += 256){
      int u = buf[i];
      int s = u & 0xFFFF, ld = u >> 16;
      int r = atomicAdd(&lcnt[ld], 1);
      stage[rolocal[ld] - rostart + r] = s;
    }
    __syncthreads();
    for (int i = t; i < seglen; i += 256) csr[rostart + i] = stage[i];
  } else {
    for (int i = t; i < cnt; i += 256){
      int u = buf[i];
      int s = u & 0xFFFF, ld = u >> 16;
      int r = atomicAdd(&lcnt[ld], 1);
      csr[rolocal[ld] + r] = s;
    }
  }
}

// ---- GAT layer 1 edge phase: wave per node, fp8 gather, 2x unrolled (MLP)
__global__ __launch_bounds__(256) void k_edge1(
    const int* __restrict__ ro, const int* __restrict__ cs,
    const unsigned char* __restrict__ xw1,
    const float* __restrict__ pas, const float* __restrict__ pad,
    const float* __restrict__ bias1,
    const float* __restrict__ g1, const float* __restrict__ b1,
    const float* __restrict__ m1, const float* __restrict__ v1,
    unsigned short* __restrict__ h1, int N)
{
  __shared__ float wt[4][CAP1][5];
  int t = threadIdx.x, w = t >> 6, lane = t & 63;
  int n = blockIdx.x * 4 + w;
  if (n >= N) return;
  int beg = ro[n], end = ro[n + 1], deg = end - beg;
  const float4 adv = *(const float4*)(pad + (size_t)n * 4);
  const bool fits = (deg <= CAP1);

  float s0 = 0.f, s1 = 0.f, s2 = 0.f, s3 = 0.f;
  for (int j = lane; j < deg; j += 64){
    int s = cs[beg + j];
    float4 a = *(const float4*)(pas + (size_t)s * 4);
    float e0 = __expf(lrelu(a.x + adv.x));
    float e1 = __expf(lrelu(a.y + adv.y));
    float e2 = __expf(lrelu(a.z + adv.z));
    float e3 = __expf(lrelu(a.w + adv.w));
    if (fits){
      wt[w][j][0] = e0; wt[w][j][1] = e1;
      wt[w][j][2] = e2; wt[w][j][3] = e3;
      wt[w][j][4] = __int_as_float(s << 8);
    }
    s0 += e0; s1 += e1; s2 += e2; s3 += e3;
  }
  s0 = wsum(s0); s1 = wsum(s1); s2 = wsum(s2); s3 = wsum(s3);

  int head = lane >> 4;
  float invh = 1.f / ((head == 0 ? s0 : head == 1 ? s1 : head == 2 ? s2 : s3) + 1e-16f);
  float aa   = head == 0 ? adv.x : head == 1 ? adv.y : head == 2 ? adv.z : adv.w;

  float a0 = 0.f, a1 = 0.f, a2 = 0.f, a3 = 0.f;
  if (fits){
    float b0 = 0.f, b1v = 0.f, b2v = 0.f, b3 = 0.f;
    int j = 0;
    for (; j + 1 < deg; j += 2){
      float wv0 = wt[w][j][head] * invh;
      int off0  = __float_as_int(wt[w][j][4]);
      float wv1 = wt[w][j+1][head] * invh;
      int off1  = __float_as_int(wt[w][j+1][4]);
      int u0 = *(const int*)(xw1 + off0 + lane * 4);
      int u1 = *(const int*)(xw1 + off1 + lane * 4);
      f32x2 lo0 = __builtin_amdgcn_cvt_pk_f32_fp8(u0, false);
      f32x2 hi0 = __builtin_amdgcn_cvt_pk_f32_fp8(u0, true);
      f32x2 lo1 = __builtin_amdgcn_cvt_pk_f32_fp8(u1, false);
      f32x2 hi1 = __builtin_amdgcn_cvt_pk_f32_fp8(u1, true);
      a0 += wv0 * lo0[0]; a1 += wv0 * lo0[1];
      a2 += wv0 * hi0[0]; a3 += wv0 * hi0[1];
      b0 += wv1 * lo1[0]; b1v += wv1 * lo1[1];
      b2v += wv1 * hi1[0]; b3 += wv1 * hi1[1];
    }
    if (j < deg){
      float wv = wt[w][j][head] * invh;
      int off = __float_as_int(wt[w][j][4]);
      int u = *(const int*)(xw1 + off + lane * 4);
      f32x2 lo = __builtin_amdgcn_cvt_pk_f32_fp8(u, false);
      f32x2 hi = __builtin_amdgcn_cvt_pk_f32_fp8(u, true);
      a0 += wv * lo[0]; a1 += wv * lo[1];
      a2 += wv * hi[0]; a3 += wv * hi[1];
    }
    a0 += b0; a1 += b1v; a2 += b2v; a3 += b3;
  } else {
    for (int j = 0; j < deg; ++j){
      int s = cs[beg + j];
      float wv = __expf(lrelu(pas[(size_t)s * 4 + head] + aa)) * invh;
      int u = *(const int*)(xw1 + (size_t)s * 256 + lane * 4);
      f32x2 lo = __builtin_amdgcn_cvt_pk_f32_fp8(u, false);
      f32x2 hi = __builtin_amdgcn_cvt_pk_f32_fp8(u, true);
      a0 += wv * lo[0]; a1 += wv * lo[1];
      a2 += wv * hi[0]; a3 += wv * hi[1];
    }
  }

  float accv[4] = {a0, a1, a2, a3};
  ushort4 outv;
  unsigned short* po = (unsigned short*)&outv;
  int j0 = lane * 4;
  #pragma unroll
  for (int i = 0; i < 4; ++i){
    int j = j0 + i;
    float o  = accv[i] + bias1[j];
    float sc = g1[j] * rsqrtf(v1[j] + 1e-5f);
    float res = (o - m1[j]) * sc + b1[j];
    po[i] = f2u16(fmaxf(res, 0.f));
  }
  *(ushort4*)(h1 + (size_t)n * 256 + j0) = outv;
}

// ---- GAT layer 2 edge phase + BN + ReLU -> h2[n,64] fp32; 4x unrolled gather
__global__ __launch_bounds__(256) void k_edge2(
    const int* __restrict__ ro, const int* __restrict__ cs,
    const unsigned char* __restrict__ xw2,
    const float* __restrict__ pas, const float* __restrict__ pad,
    const float* __restrict__ bias2,
    const float* __restrict__ g2, const float* __restrict__ b2,
    const float* __restrict__ m2, const float* __restrict__ v2,
    float* __restrict__ h2, int N)
{
  __shared__ float wt[4][CAP2][2];
  int t = threadIdx.x, w = t >> 6, lane = t & 63;
  int n = blockIdx.x * 4 + w;
  if (n >= N) return;
  int beg = ro[n], end = ro[n + 1], deg = end - beg;
  float adv = pad[n];
  const bool fits = (deg <= CAP2);

  float dh = 0.f;
  for (int j = lane; j < deg; j += 64){
    int s = cs[beg + j];
    float e = __expf(lrelu(pas[s] + adv));
    if (fits){
      wt[w][j][0] = e;
      wt[w][j][1] = __int_as_float(s << 6);
    }
    dh += e;
  }
  dh = wsum(dh);
  float inv = 1.f / (dh + 1e-16f);

  float acc = 0.f;
  if (fits){
    float p0 = 0.f, p1 = 0.f, p2 = 0.f, p3 = 0.f;
    int j = 0;
    for (; j + 3 < deg; j += 4){
      float w0 = wt[w][j][0],   w1 = wt[w][j+1][0];
      float w2 = wt[w][j+2][0], w3 = wt[w][j+3][0];
      int o0 = __float_as_int(wt[w][j][1]);
      int o1 = __float_as_int(wt[w][j+1][1]);
      int o2 = __float_as_int(wt[w][j+2][1]);
      int o3 = __float_as_int(wt[w][j+3][1]);
      unsigned char c0 = xw2[o0 + lane];
      unsigned char c1 = xw2[o1 + lane];
      unsigned char c2 = xw2[o2 + lane];
      unsigned char c3 = xw2[o3 + lane];
      p0 += w0 * fp82f(c0);
      p1 += w1 * fp82f(c1);
      p2 += w2 * fp82f(c2);
      p3 += w3 * fp82f(c3);
    }
    for (; j < deg; ++j){
      float wv = wt[w][j][0];
      int off = __float_as_int(wt[w][j][1]);
      p0 += wv * fp82f(xw2[off + lane]);
    }
    acc = ((p0 + p1) + (p2 + p3)) * inv;
  } else {
    for (int j = 0; j < deg; ++j){
      int s = cs[beg + j];
      float wv = __expf(lrelu(pas[s] + adv)) * inv;
      acc += wv * fp82f(xw2[(size_t)s * 64 + lane]);
    }
  }

  float o  = acc + bias2[lane];
  float sc = g2[lane] * rsqrtf(v2[lane] + 1e-5f);
  h2[(size_t)n * 64 + lane] = fmaxf((o - m2[lane]) * sc + b2[lane], 0.f);
}

// ---- segmented mean pool: one block per graph (batch is sorted)
__global__ __launch_bounds__(256) void k_pool(
    const float* __restrict__ h2, const int* __restrict__ batch,
    float* __restrict__ pool, int N)
{
  int g = blockIdx.x;
  int t = threadIdx.x, c = t & 63, w = t >> 6;
  int lo = 0, hi = N;
  while (lo < hi){ int mid = (lo + hi) >> 1; if (batch[mid] < g) lo = mid + 1; else hi = mid; }
  int lo2 = lo, hi2 = N;
  while (lo2 < hi2){ int mid = (lo2 + hi2) >> 1; if (batch[mid] < g + 1) lo2 = mid + 1; else hi2 = mid; }
  float s = 0.f;
  for (int r = lo + w; r < lo2; r += 4) s += h2[(size_t)r * 64 + c];
  __shared__ float sd[4][64];
  sd[w][c] = s;
  __syncthreads();
  if (w == 0){
    float tot = sd[0][c] + sd[1][c] + sd[2][c] + sd[3][c];
    float cntf = (float)(lo2 - lo);
    pool[g * 64 + c] = tot / fmaxf(cntf, 1.f);
  }
}

// ---- classifier + log_softmax: one wave per graph, fp32 output
__global__ __launch_bounds__(64) void k_final(
    const float* __restrict__ pool,
    const float* __restrict__ Wc1, const float* __restrict__ bc1,
    const float* __restrict__ Wc2, const float* __restrict__ bc2,
    float* __restrict__ out)
{
  int g = blockIdx.x, c = threadIdx.x;
  __shared__ float gr[64];
  gr[c] = pool[g * 64 + c];
  __syncthreads();
  float a = bc1[c];
  for (int k = 0; k < 64; ++k) a += gr[k] * Wc1[k * 64 + c];
  float hc = fmaxf(a, 0.f);
  float p0 = hc * Wc2[c * 2 + 0];
  float p1 = hc * Wc2[c * 2 + 1];
  p0 = wsum(p0); p1 = wsum(p1);
  if (c == 0){
    float l0 = p0 + bc2[0];
    float l1 = p1 + bc2[1];
    float mx = fmaxf(l0, l1);
    float lse = mx + logf(expf(l0 - mx) + expf(l1 - mx));
    out[g * 2 + 0] = l0 - lse;
    out[g * 2 + 1] = l1 - lse;
  }
}

extern "C" void kernel_launch(void* const* d_in, const int* in_sizes, int n_in,
                              void* d_out, int out_size, void* d_ws, size_t ws_size,
                              hipStream_t stream)
{
  const float* x     = (const float*)d_in[0];
  const int*   ei    = (const int*)d_in[1];
  const int*   batch = (const int*)d_in[2];
  const float* W1    = (const float*)d_in[3];
  const float* asrc1 = (const float*)d_in[4];
  const float* adst1 = (const float*)d_in[5];
  const float* bias1 = (const float*)d_in[6];
  const float* bn1g  = (const float*)d_in[7];
  const float* bn1b  = (const float*)d_in[8];
  const float* bn1m  = (const float*)d_in[9];
  const float* bn1v  = (const float*)d_in[10];
  const float* W2    = (const float*)d_in[11];
  const float* asrc2 = (const float*)d_in[12];
  const float* adst2 = (const float*)d_in[13];
  const float* bias2 = (const float*)d_in[14];
  const float* bn2g  = (const float*)d_in[15];
  const float* bn2b  = (const float*)d_in[16];
  const float* bn2m  = (const float*)d_in[17];
  const float* bn2v  = (const float*)d_in[18];
  const float* Wc1   = (const float*)d_in[19];
  const float* bc1   = (const float*)d_in[20];
  const float* Wc2   = (const float*)d_in[21];
  const float* bc2   = (const float*)d_in[22];
  float* out = (float*)d_out;

  const int N  = in_sizes[0] / 128;
  const int E  = in_sizes[1] / 2;
  const int ET = E + N;
  const int NB = (N + 127) >> 7;   // 128-node bins

  char* p = (char*)d_ws;
  auto take = [&](size_t bytes) -> void* {
    void* q = (void*)p;
    p += ((bytes + 255) & ~(size_t)255);
    return q;
  };
  // zero-initialized region (cursor + bincur + ovfcnt)
  int*   cursor = (int*)  take((size_t)N * 4);
  int*   bincur = (int*)  take((size_t)NB * 16 * 4);
  int*   ovfcnt = (int*)  take(256);
  size_t zbytes = (size_t)(p - (char*)d_ws);
  int*   count  = (int*)  take((size_t)N * 4);
  float* pool   = (float*)take(64 * 64 * 4);
  int*   ro     = (int*)  take((size_t)(N + 1) * 4);
  int*   bsum   = (int*)  take(1024);
  float* as1    = (float*)take((size_t)N * 16);
  float* ad1    = (float*)take((size_t)N * 16);
  float* as2    = (float*)take((size_t)N * 4);
  float* ad2    = (float*)take((size_t)N * 4);
  unsigned char*  xw1 = (unsigned char*) take((size_t)N * 256);
  unsigned short* h1  = (unsigned short*)take((size_t)N * 256 * 2);
  float* h2     = (float*)take((size_t)N * 64 * 4);
  int*   csr    = (int*)  take((size_t)ET * 4);
  int*   binbuf = (int*)  take((size_t)NB * CAPB * 4);
  int2*  ovfbuf = (int2*) take((size_t)OVFCAP * 8);
  unsigned short* B1p = (unsigned short*)take(32768 * 2);
  unsigned short* B2p = (unsigned short*)take(16384 * 2);
  unsigned short* xb  = (unsigned short*)h2;  // alias: xb dead before k_edge2 writes h2
  unsigned char*  xw2 = xw1;                  // alias: xw1 dead after k_edge1
  (void)n_in; (void)ws_size; (void)out_size;

  int zw = (int)(zbytes / 4);
  k_zero<<<dim3((zw + 255) / 256), dim3(256), 0, stream>>>((int*)d_ws, zw);
  int n4 = N * 32;  // N*128/4
  int cvtBlocks = (n4 + 255) / 256;
  k_prep<<<dim3(cvtBlocks + 192), dim3(256), 0, stream>>>(x, xb, n4, W1, B1p, W2, B2p, cvtBlocks);
  k_binscat<<<dim3((ET + EPB - 1) / EPB), dim3(1024), 0, stream>>>(ei, bincur, binbuf,
                                                                   ovfcnt, ovfbuf, E, ET, NB);
  k_cnt<<<dim3(NB), dim3(256), 0, stream>>>(bincur, binbuf, count, N);
  k_cntovf<<<dim3(8), dim3(256), 0, stream>>>(ovfcnt, ovfbuf, count);
  int nb = (N + 255) / 256;
  k_scan1<<<dim3(nb), dim3(256), 0, stream>>>(count, ro, bsum, N);
  k_scan2<<<dim3(1), dim3(256), 0, stream>>>(bsum, nb);
  k_scan3<<<dim3(nb), dim3(256), 0, stream>>>(ro, bsum, N, ET);
  k_binsort<<<dim3(NB), dim3(256), 0, stream>>>(bincur, binbuf, ro, csr, N);
  k_ovfscat<<<dim3(8), dim3(256), 0, stream>>>(ovfcnt, ovfbuf, ro, cursor, csr);
  k_gemm1m<<<dim3((N + 63) / 64), dim3(256), 0, stream>>>(xb, (const bf16x8*)B1p,
                                                          asrc1, adst1, xw1, as1, ad1, N);
  k_edge1<<<dim3((N + 3) / 4), dim3(256), 0, stream>>>(ro, csr, xw1, as1, ad1,
                                                       bias1, bn1g, bn1b, bn1m, bn1v, h1, N);
  k_gemm2m<<<dim3((N + 63) / 64), dim3(256), 0, stream>>>(h1, (const bf16x8*)B2p,
                                                          asrc2, adst2, xw2, as2, ad2, N);
  k_edge2<<<dim3((N + 3) / 4), dim3(256), 0, stream>>>(ro, csr, xw2, as2, ad2,
                                                       bias2, bn2g, bn2b, bn2m, bn2v, h2, N);
  k_pool<<<dim3(64), dim3(256), 0, stream>>>(h2, batch, pool, N);
  k_final<<<dim3(64), dim3(64), 0, stream>>>(pool, Wc1, bc1, Wc2, bc2, out);
}

// Round 16
// 358.230 us; speedup vs baseline: 1.0441x; 1.0441x over previous
//
#include <hip/hip_runtime.h>

#define NEG_SLOPE 0.2f
#define CAP1 224
#define CAP2 224
#define CAPB 5120    // per-bin capacity (bin mean ~4224, sd ~65 -> +13 sd)
#define EPB  16384   // edges per binscat block
#define OVFCAP 65536

typedef short bf16x8 __attribute__((ext_vector_type(8)));
typedef float f32x4  __attribute__((ext_vector_type(4)));
typedef float f32x2  __attribute__((ext_vector_type(2)));

static __device__ __forceinline__ float u16f(unsigned short u){
  union { unsigned int i; float f; } v; v.i = ((unsigned int)u) << 16; return v.f;
}
static __device__ __forceinline__ unsigned short f2u16(float f){
  union { float f; unsigned int i; } v; v.f = f;
  unsigned int r = (v.i + 0x7FFFu + ((v.i >> 16) & 1u)) >> 16;
  return (unsigned short)r;
}
static __device__ __forceinline__ unsigned char f2fp8(float f){
  int w = __builtin_amdgcn_cvt_pk_fp8_f32(f, f, 0, false);
  return (unsigned char)(w & 0xFF);
}
static __device__ __forceinline__ float fp82f(unsigned char b){
  f32x2 d = __builtin_amdgcn_cvt_pk_f32_fp8((int)b, false);
  return d[0];
}
static __device__ __forceinline__ float wsum(float v){
  #pragma unroll
  for (int o = 32; o > 0; o >>= 1) v += __shfl_xor(v, o, 64);
  return v;
}
static __device__ __forceinline__ float qsum(float v){
  #pragma unroll
  for (int o = 1; o < 16; o <<= 1) v += __shfl_xor(v, o, 64);
  return v;
}
static __device__ __forceinline__ float lrelu(float e){
  return e >= 0.f ? e : NEG_SLOPE * e;
}

// ---- fused prep: zero ws counters, cvt x->bf16, pack W1, pack W2 (grid-sectioned)
__global__ __launch_bounds__(256) void k_prep(int* __restrict__ zp, int nzero, int zeroBlocks,
                                              const float* __restrict__ x,
                                              unsigned short* __restrict__ xb, int n4,
                                              const float* __restrict__ W1,
                                              unsigned short* __restrict__ B1p,
                                              const float* __restrict__ W2,
                                              unsigned short* __restrict__ B2p,
                                              int cvtBlocks){
  int b = blockIdx.x, t = threadIdx.x;
  if (b < zeroBlocks){
    int i = b * 256 + t;
    if (i < nzero) zp[i] = 0;
  } else if (b < zeroBlocks + cvtBlocks){
    int i = (b - zeroBlocks) * 256 + t;
    if (i >= n4) return;
    float4 f = ((const float4*)x)[i];
    ushort4 u;
    u.x = f2u16(f.x); u.y = f2u16(f.y); u.z = f2u16(f.z); u.w = f2u16(f.w);
    ((ushort4*)xb)[i] = u;
  } else if (b < zeroBlocks + cvtBlocks + 128){
    int idx = (b - zeroBlocks - cvtBlocks) * 256 + t;   // [0, 32768)
    int j = idx & 7, lane = (idx >> 3) & 63, nt = (idx >> 9) & 15, kc = idx >> 13;
    int k = kc*32 + (lane >> 4)*8 + j;
    int n = nt*16 + (lane & 15);
    B1p[idx] = f2u16(W1[k*256 + n]);
  } else {
    int idx = (b - zeroBlocks - cvtBlocks - 128) * 256 + t;  // [0, 16384)
    int j = idx & 7, lane = (idx >> 3) & 63, nt = (idx >> 9) & 3, kc = idx >> 11;
    int k = kc*32 + (lane >> 4)*8 + j;
    int n = nt*16 + (lane & 15);
    B2p[idx] = f2u16(W2[k*64 + n]);
  }
}

// ---- layer1 GEMM via MFMA: xw1 = x @ W1 (fp8 out), alpha vectors fp32 [N,4]
__global__ __launch_bounds__(256) void k_gemm1m(
    const unsigned short* __restrict__ xb, const bf16x8* __restrict__ B1p,
    const float* __restrict__ asrc, const float* __restrict__ adst,
    unsigned char* __restrict__ xw1, float* __restrict__ oas, float* __restrict__ oad,
    int N)
{
  __shared__ unsigned short xs[64][136];
  int t = threadIdx.x;
  int m0 = blockIdx.x * 64;
  #pragma unroll
  for (int i = 0; i < 4; ++i){
    int flat = t + i*256;
    int r = flat >> 4, c8 = flat & 15;
    uint4 v = make_uint4(0,0,0,0);
    if (m0 + r < N) v = *(const uint4*)(xb + (size_t)(m0 + r)*128 + c8*8);
    *(uint4*)&xs[r][c8*8] = v;
  }
  __syncthreads();
  int w = t >> 6, l = t & 63;
  int quad = l >> 4, ml = l & 15;

  f32x4 acc[16];
  #pragma unroll
  for (int i = 0; i < 16; ++i){ acc[i][0]=0.f; acc[i][1]=0.f; acc[i][2]=0.f; acc[i][3]=0.f; }

  #pragma unroll
  for (int kc = 0; kc < 4; ++kc){
    bf16x8 a = *(const bf16x8*)&xs[w*16 + ml][kc*32 + quad*8];
    #pragma unroll
    for (int nt = 0; nt < 16; ++nt){
      bf16x8 b = B1p[(kc*16 + nt)*64 + l];
      acc[nt] = __builtin_amdgcn_mfma_f32_16x16x32_bf16(a, b, acc[nt], 0, 0, 0);
    }
  }

  float as_h[4][4], ad_h[4][4];
  #pragma unroll
  for (int h = 0; h < 4; ++h)
    #pragma unroll
    for (int r = 0; r < 4; ++r){ as_h[h][r] = 0.f; ad_h[h][r] = 0.f; }
  #pragma unroll
  for (int nt = 0; nt < 16; ++nt){
    float vs = asrc[nt*16 + ml], vd = adst[nt*16 + ml];
    int h = nt >> 2;
    #pragma unroll
    for (int r = 0; r < 4; ++r){
      as_h[h][r] += acc[nt][r] * vs;
      ad_h[h][r] += acc[nt][r] * vd;
    }
  }
  #pragma unroll
  for (int h = 0; h < 4; ++h)
    #pragma unroll
    for (int r = 0; r < 4; ++r){ as_h[h][r] = qsum(as_h[h][r]); ad_h[h][r] = qsum(ad_h[h][r]); }

  int baserow = m0 + w*16 + quad*4;
  if (ml == 0){
    #pragma unroll
    for (int r = 0; r < 4; ++r){
      int node = baserow + r;
      if (node < N){
        *(float4*)(oas + (size_t)node*4) = make_float4(as_h[0][r], as_h[1][r], as_h[2][r], as_h[3][r]);
        *(float4*)(oad + (size_t)node*4) = make_float4(ad_h[0][r], ad_h[1][r], ad_h[2][r], ad_h[3][r]);
      }
    }
  }

  // fp8 epilogue via LDS staging
  __syncthreads();
  unsigned char* sb = (unsigned char*)&xs[0][0]; // [64][256] bytes
  #pragma unroll
  for (int r = 0; r < 4; ++r){
    int lrow = w*16 + quad*4 + r;
    #pragma unroll
    for (int nt = 0; nt < 16; ++nt)
      sb[lrow*256 + nt*16 + ml] = f2fp8(acc[nt][r]);
  }
  __syncthreads();
  #pragma unroll
  for (int i = 0; i < 4; ++i){
    int flat = t + i*256;
    int row = flat >> 4, c16 = flat & 15;
    int node = m0 + row;
    if (node < N)
      *(uint4*)(xw1 + (size_t)node*256 + c16*16) = *(const uint4*)(sb + row*256 + c16*16);
  }
}

// ---- layer2 GEMM via MFMA: xw2 = h1 @ W2 (fp8 out), alpha scalars
__global__ __launch_bounds__(256) void k_gemm2m(
    const unsigned short* __restrict__ h1, const bf16x8* __restrict__ B2p,
    const float* __restrict__ asrc, const float* __restrict__ adst,
    unsigned char* __restrict__ xw2, float* __restrict__ oas, float* __restrict__ oad,
    int N)
{
  __shared__ unsigned short ys[64][264];
  int t = threadIdx.x;
  int m0 = blockIdx.x * 64;
  #pragma unroll
  for (int i = 0; i < 8; ++i){
    int flat = t + i*256;
    int r = flat >> 5, c8 = flat & 31;
    uint4 v = make_uint4(0,0,0,0);
    if (m0 + r < N) v = *(const uint4*)(h1 + (size_t)(m0 + r)*256 + c8*8);
    *(uint4*)&ys[r][c8*8] = v;
  }
  __syncthreads();
  int w = t >> 6, l = t & 63;
  int quad = l >> 4, ml = l & 15;

  f32x4 acc[4];
  #pragma unroll
  for (int i = 0; i < 4; ++i){ acc[i][0]=0.f; acc[i][1]=0.f; acc[i][2]=0.f; acc[i][3]=0.f; }

  #pragma unroll
  for (int kc = 0; kc < 8; ++kc){
    bf16x8 a = *(const bf16x8*)&ys[w*16 + ml][kc*32 + quad*8];
    #pragma unroll
    for (int nt = 0; nt < 4; ++nt){
      bf16x8 b = B2p[(kc*4 + nt)*64 + l];
      acc[nt] = __builtin_amdgcn_mfma_f32_16x16x32_bf16(a, b, acc[nt], 0, 0, 0);
    }
  }

  float as_p[4] = {0,0,0,0}, ad_p[4] = {0,0,0,0};
  #pragma unroll
  for (int nt = 0; nt < 4; ++nt){
    float vs = asrc[nt*16 + ml], vd = adst[nt*16 + ml];
    #pragma unroll
    for (int r = 0; r < 4; ++r){
      as_p[r] += acc[nt][r] * vs;
      ad_p[r] += acc[nt][r] * vd;
    }
  }
  #pragma unroll
  for (int r = 0; r < 4; ++r){ as_p[r] = qsum(as_p[r]); ad_p[r] = qsum(ad_p[r]); }

  int baserow = m0 + w*16 + quad*4;
  if (ml == 0){
    #pragma unroll
    for (int r = 0; r < 4; ++r){
      int node = baserow + r;
      if (node < N){ oas[node] = as_p[r]; oad[node] = ad_p[r]; }
    }
  }

  // fp8 epilogue via LDS staging
  __syncthreads();
  unsigned char* sb = (unsigned char*)&ys[0][0]; // [64][64] bytes
  #pragma unroll
  for (int r = 0; r < 4; ++r){
    int lrow = w*16 + quad*4 + r;
    #pragma unroll
    for (int nt = 0; nt < 4; ++nt)
      sb[lrow*64 + nt*16 + ml] = f2fp8(acc[nt][r]);
  }
  __syncthreads();
  {
    int flat = t;
    int row = flat >> 2, c16 = flat & 3;
    int node = m0 + row;
    if (node < N)
      *(uint4*)(xw2 + (size_t)node*64 + c16*16) = *(const uint4*)(sb + row*64 + c16*16);
  }
}

// ---- scans over per-node counts -> CSR row offsets
__global__ __launch_bounds__(256) void k_scan1(const int* __restrict__ count,
                                               int* __restrict__ ro, int* __restrict__ bsum, int N){
  __shared__ int sd[256];
  int t = threadIdx.x, b = blockIdx.x, i = b*256 + t;
  int v = (i < N) ? count[i] : 0;
  sd[t] = v; __syncthreads();
  for (int o = 1; o < 256; o <<= 1){
    int x = (t >= o) ? sd[t - o] : 0;
    __syncthreads();
    sd[t] += x;
    __syncthreads();
  }
  if (i < N) ro[i] = sd[t] - v;  // exclusive
  if (t == 255) bsum[b] = sd[255];
}

__global__ __launch_bounds__(256) void k_scan2(int* __restrict__ bsum, int nb){
  __shared__ int sd[256];
  int t = threadIdx.x;
  int v = (t < nb) ? bsum[t] : 0;
  sd[t] = v; __syncthreads();
  for (int o = 1; o < 256; o <<= 1){
    int x = (t >= o) ? sd[t - o] : 0;
    __syncthreads();
    sd[t] += x;
    __syncthreads();
  }
  if (t < nb) bsum[t] = sd[t] - v;  // exclusive
}

__global__ __launch_bounds__(256) void k_scan3(int* __restrict__ ro,
                                               const int* __restrict__ bsum, int N, int ET){
  int b = blockIdx.x, t = threadIdx.x, i = b*256 + t;
  if (i < N) ro[i] += bsum[b];
  if (b == 0 && t == 0) ro[N] = ET;
}

// ---- Pass B: block-chunked reservation scatter.
__global__ __launch_bounds__(1024) void k_binscat(const int* __restrict__ ei,
                                                  int* __restrict__ bincur,
                                                  int* __restrict__ binbuf,
                                                  int* __restrict__ ovfcnt,
                                                  int2* __restrict__ ovfbuf,
                                                  int E, int ET, int NB){
  __shared__ int lhist[512];
  __shared__ int lbase[512];
  __shared__ int lcur[512];
  int t = threadIdx.x;
  int base = blockIdx.x * EPB;
  for (int i = t; i < 512; i += 1024){ lhist[i] = 0; lcur[i] = 0; }
  __syncthreads();

  int myb[16], mypay[16];
  #pragma unroll
  for (int k = 0; k < 16; ++k){
    int i = base + t + k*1024;
    int b = -1, pay = 0;
    if (i < ET){
      int s, d;
      if (i < E){ s = ei[i]; d = ei[E + i]; }
      else      { s = i - E; d = i - E; }
      b = d >> 7;
      pay = ((d & 127) << 16) | s;
      atomicAdd(&lhist[b], 1);
    }
    myb[k] = b; mypay[k] = pay;
  }
  __syncthreads();

  for (int i = t; i < NB; i += 1024){
    int h = lhist[i];
    if (h > 0) lbase[i] = atomicAdd(&bincur[i * 16], h);
  }
  __syncthreads();

  #pragma unroll
  for (int k = 0; k < 16; ++k){
    int b = myb[k];
    if (b < 0) continue;
    int pos = lbase[b] + atomicAdd(&lcur[b], 1);
    if (pos < CAPB){
      binbuf[(size_t)b * CAPB + pos] = mypay[k];
    } else {
      int d = (b << 7) | (mypay[k] >> 16);
      int s = mypay[k] & 0xFFFF;
      int idx = atomicAdd(ovfcnt, 1);
      if (idx < OVFCAP) ovfbuf[idx] = make_int2(d, s);
    }
  }
}

// ---- per-node counts from binbuf: one block per bin, LDS histogram, coalesced write.
__global__ __launch_bounds__(256) void k_cnt(const int* __restrict__ bincur,
                                             const int* __restrict__ binbuf,
                                             int* __restrict__ count, int N){
  __shared__ int lcnt[128];
  int b = blockIdx.x, t = threadIdx.x;
  int base = b << 7;
  int wn = N - base; if (wn > 128) wn = 128;
  if (wn <= 0) return;
  for (int i = t; i < wn; i += 256) lcnt[i] = 0;
  __syncthreads();
  int total = bincur[b * 16];
  int cnt = total < CAPB ? total : CAPB;
  const int* buf = binbuf + (size_t)b * CAPB;
  for (int i = t; i < cnt; i += 256) atomicAdd(&lcnt[buf[i] >> 16], 1);
  __syncthreads();
  for (int i = t; i < wn; i += 256) count[base + i] = lcnt[i];
}

// ---- count overflow-list entries (normally zero iterations)
__global__ __launch_bounds__(256) void k_cntovf(const int* __restrict__ ovfcnt,
                                                const int2* __restrict__ ovfbuf,
                                                int* __restrict__ count){
  int n = ovfcnt[0]; if (n > OVFCAP) n = OVFCAP;
  for (int i = blockIdx.x*256 + threadIdx.x; i < n; i += gridDim.x*256)
    atomicAdd(&count[ovfbuf[i].x], 1);
}

// ---- Pass C: blocks [0,NB) sort bins into csr; blocks [NB,NB+8) drain overflow list
__global__ __launch_bounds__(256) void k_binsort(const int* __restrict__ bincur,
                                                 const int* __restrict__ binbuf,
                                                 const int* __restrict__ ro,
                                                 int* __restrict__ csr,
                                                 const int* __restrict__ ovfcnt,
                                                 const int2* __restrict__ ovfbuf,
                                                 int* __restrict__ cursor,
                                                 int N, int NB){
  int b = blockIdx.x, t = threadIdx.x;
  if (b >= NB){
    // overflow drain: fill dst segments from the END (disjoint from staged region)
    int n = ovfcnt[0]; if (n > OVFCAP) n = OVFCAP;
    for (int i = (b - NB)*256 + t; i < n; i += 8*256){
      int d = ovfbuf[i].x, s = ovfbuf[i].y;
      int pos = atomicAdd(&cursor[d], 1);
      csr[ro[d + 1] - 1 - pos] = s;
    }
    return;
  }
  __shared__ int rolocal[129];
  __shared__ int lcnt[128];
  __shared__ int stage[CAPB];
  int base = b << 7;
  int wn = N - base; if (wn > 128) wn = 128;
  if (wn <= 0) return;
  for (int i = t; i <= wn; i += 256) rolocal[i] = ro[base + i];
  for (int i = t; i < wn; i += 256) lcnt[i] = 0;
  __syncthreads();
  int rostart = rolocal[0];
  int seglen = rolocal[wn] - rostart;
  int total = bincur[b * 16];
  int cnt = total < CAPB ? total : CAPB;
  bool ovf = (seglen > CAPB) || (total > CAPB);
  const int* buf = binbuf + (size_t)b * CAPB;

  if (!ovf){
    for (int i = t; i < cnt; i += 256){
      int u = buf[i];
      int s = u & 0xFFFF, ld = u >> 16;
      int r = atomicAdd(&lcnt[ld], 1);
      stage[rolocal[ld] - rostart + r] = s;
    }
    __syncthreads();
    for (int i = t; i < seglen; i += 256) csr[rostart + i] = stage[i];
  } else {
    for (int i = t; i < cnt; i += 256){
      int u = buf[i];
      int s = u & 0xFFFF, ld = u >> 16;
      int r = atomicAdd(&lcnt[ld], 1);
      csr[rolocal[ld] + r] = s;
    }
  }
}

// ---- GAT layer 1 edge phase: one WAVE per dst node (4 nodes/block), fp8 gather
__global__ __launch_bounds__(256) void k_edge1(
    const int* __restrict__ ro, const int* __restrict__ cs,
    const unsigned char* __restrict__ xw1,
    const float* __restrict__ pas, const float* __restrict__ pad,
    const float* __restrict__ bias1,
    const float* __restrict__ g1, const float* __restrict__ b1,
    const float* __restrict__ m1, const float* __restrict__ v1,
    unsigned short* __restrict__ h1, int N)
{
  __shared__ float wt[4][CAP1][5];
  int t = threadIdx.x, w = t >> 6, lane = t & 63;
  int n = blockIdx.x * 4 + w;
  if (n >= N) return;
  int beg = ro[n], end = ro[n + 1], deg = end - beg;
  const float4 adv = *(const float4*)(pad + (size_t)n * 4);
  const bool fits = (deg <= CAP1);

  float s0 = 0.f, s1 = 0.f, s2 = 0.f, s3 = 0.f;
  for (int j = lane; j < deg; j += 64){
    int s = cs[beg + j];
    float4 a = *(const float4*)(pas + (size_t)s * 4);
    float e0 = __expf(lrelu(a.x + adv.x));
    float e1 = __expf(lrelu(a.y + adv.y));
    float e2 = __expf(lrelu(a.z + adv.z));
    float e3 = __expf(lrelu(a.w + adv.w));
    if (fits){
      wt[w][j][0] = e0; wt[w][j][1] = e1;
      wt[w][j][2] = e2; wt[w][j][3] = e3;
      wt[w][j][4] = __int_as_float(s << 8);
    }
    s0 += e0; s1 += e1; s2 += e2; s3 += e3;
  }
  s0 = wsum(s0); s1 = wsum(s1); s2 = wsum(s2); s3 = wsum(s3);

  int head = lane >> 4;
  float invh = 1.f / ((head == 0 ? s0 : head == 1 ? s1 : head == 2 ? s2 : s3) + 1e-16f);
  float aa   = head == 0 ? adv.x : head == 1 ? adv.y : head == 2 ? adv.z : adv.w;

  float a0 = 0.f, a1 = 0.f, a2 = 0.f, a3 = 0.f;
  if (fits){
    for (int j = 0; j < deg; ++j){
      float wv = wt[w][j][head] * invh;
      int off = __float_as_int(wt[w][j][4]);
      int u = *(const int*)(xw1 + off + lane * 4);
      f32x2 lo = __builtin_amdgcn_cvt_pk_f32_fp8(u, false);
      f32x2 hi = __builtin_amdgcn_cvt_pk_f32_fp8(u, true);
      a0 += wv * lo[0]; a1 += wv * lo[1];
      a2 += wv * hi[0]; a3 += wv * hi[1];
    }
  } else {
    for (int j = 0; j < deg; ++j){
      int s = cs[beg + j];
      float wv = __expf(lrelu(pas[(size_t)s * 4 + head] + aa)) * invh;
      int u = *(const int*)(xw1 + (size_t)s * 256 + lane * 4);
      f32x2 lo = __builtin_amdgcn_cvt_pk_f32_fp8(u, false);
      f32x2 hi = __builtin_amdgcn_cvt_pk_f32_fp8(u, true);
      a0 += wv * lo[0]; a1 += wv * lo[1];
      a2 += wv * hi[0]; a3 += wv * hi[1];
    }
  }

  float accv[4] = {a0, a1, a2, a3};
  ushort4 outv;
  unsigned short* po = (unsigned short*)&outv;
  int j0 = lane * 4;
  #pragma unroll
  for (int i = 0; i < 4; ++i){
    int j = j0 + i;
    float o  = accv[i] + bias1[j];
    float sc = g1[j] * rsqrtf(v1[j] + 1e-5f);
    float res = (o - m1[j]) * sc + b1[j];
    po[i] = f2u16(fmaxf(res, 0.f));
  }
  *(ushort4*)(h1 + (size_t)n * 256 + j0) = outv;
}

// ---- GAT layer 2 edge phase + BN + ReLU -> h2[n,64] fp32, wave per node, fp8 gather
__global__ __launch_bounds__(256) void k_edge2(
    const int* __restrict__ ro, const int* __restrict__ cs,
    const unsigned char* __restrict__ xw2,
    const float* __restrict__ pas, const float* __restrict__ pad,
    const float* __restrict__ bias2,
    const float* __restrict__ g2, const float* __restrict__ b2,
    const float* __restrict__ m2, const float* __restrict__ v2,
    float* __restrict__ h2, int N)
{
  __shared__ float wt[4][CAP2][2];
  int t = threadIdx.x, w = t >> 6, lane = t & 63;
  int n = blockIdx.x * 4 + w;
  if (n >= N) return;
  int beg = ro[n], end = ro[n + 1], deg = end - beg;
  float adv = pad[n];
  const bool fits = (deg <= CAP2);

  float dh = 0.f;
  for (int j = lane; j < deg; j += 64){
    int s = cs[beg + j];
    float e = __expf(lrelu(pas[s] + adv));
    if (fits){
      wt[w][j][0] = e;
      wt[w][j][1] = __int_as_float(s << 6);
    }
    dh += e;
  }
  dh = wsum(dh);
  float inv = 1.f / (dh + 1e-16f);

  float acc = 0.f;
  if (fits){
    for (int j = 0; j < deg; ++j){
      float wv = wt[w][j][0] * inv;
      int off = __float_as_int(wt[w][j][1]);
      acc += wv * fp82f(xw2[off + lane]);
    }
  } else {
    for (int j = 0; j < deg; ++j){
      int s = cs[beg + j];
      float wv = __expf(lrelu(pas[s] + adv)) * inv;
      acc += wv * fp82f(xw2[(size_t)s * 64 + lane]);
    }
  }

  float o  = acc + bias2[lane];
  float sc = g2[lane] * rsqrtf(v2[lane] + 1e-5f);
  h2[(size_t)n * 64 + lane] = fmaxf((o - m2[lane]) * sc + b2[lane], 0.f);
}

// ---- segmented mean pool: one block per graph (batch is sorted)
__global__ __launch_bounds__(256) void k_pool(
    const float* __restrict__ h2, const int* __restrict__ batch,
    float* __restrict__ pool, int N)
{
  int g = blockIdx.x;
  int t = threadIdx.x, c = t & 63, w = t >> 6;
  int lo = 0, hi = N;
  while (lo < hi){ int mid = (lo + hi) >> 1; if (batch[mid] < g) lo = mid + 1; else hi = mid; }
  int lo2 = lo, hi2 = N;
  while (lo2 < hi2){ int mid = (lo2 + hi2) >> 1; if (batch[mid] < g + 1) lo2 = mid + 1; else hi2 = mid; }
  float s = 0.f;
  for (int r = lo + w; r < lo2; r += 4) s += h2[(size_t)r * 64 + c];
  __shared__ float sd[4][64];
  sd[w][c] = s;
  __syncthreads();
  if (w == 0){
    float tot = sd[0][c] + sd[1][c] + sd[2][c] + sd[3][c];
    float cntf = (float)(lo2 - lo);
    pool[g * 64 + c] = tot / fmaxf(cntf, 1.f);
  }
}

// ---- classifier + log_softmax: one wave per graph, fp32 output
__global__ __launch_bounds__(64) void k_final(
    const float* __restrict__ pool,
    const float* __restrict__ Wc1, const float* __restrict__ bc1,
    const float* __restrict__ Wc2, const float* __restrict__ bc2,
    float* __restrict__ out)
{
  int g = blockIdx.x, c = threadIdx.x;
  __shared__ float gr[64];
  gr[c] = pool[g * 64 + c];
  __syncthreads();
  float a = bc1[c];
  for (int k = 0; k < 64; ++k) a += gr[k] * Wc1[k * 64 + c];
  float hc = fmaxf(a, 0.f);
  float p0 = hc * Wc2[c * 2 + 0];
  float p1 = hc * Wc2[c * 2 + 1];
  p0 = wsum(p0); p1 = wsum(p1);
  if (c == 0){
    float l0 = p0 + bc2[0];
    float l1 = p1 + bc2[1];
    float mx = fmaxf(l0, l1);
    float lse = mx + logf(expf(l0 - mx) + expf(l1 - mx));
    out[g * 2 + 0] = l0 - lse;
    out[g * 2 + 1] = l1 - lse;
  }
}

extern "C" void kernel_launch(void* const* d_in, const int* in_sizes, int n_in,
                              void* d_out, int out_size, void* d_ws, size_t ws_size,
                              hipStream_t stream)
{
  const float* x     = (const float*)d_in[0];
  const int*   ei    = (const int*)d_in[1];
  const int*   batch = (const int*)d_in[2];
  const float* W1    = (const float*)d_in[3];
  const float* asrc1 = (const float*)d_in[4];
  const float* adst1 = (const float*)d_in[5];
  const float* bias1 = (const float*)d_in[6];
  const float* bn1g  = (const float*)d_in[7];
  const float* bn1b  = (const float*)d_in[8];
  const float* bn1m  = (const float*)d_in[9];
  const float* bn1v  = (const float*)d_in[10];
  const float* W2    = (const float*)d_in[11];
  const float* asrc2 = (const float*)d_in[12];
  const float* adst2 = (const float*)d_in[13];
  const float* bias2 = (const float*)d_in[14];
  const float* bn2g  = (const float*)d_in[15];
  const float* bn2b  = (const float*)d_in[16];
  const float* bn2m  = (const float*)d_in[17];
  const float* bn2v  = (const float*)d_in[18];
  const float* Wc1   = (const float*)d_in[19];
  const float* bc1   = (const float*)d_in[20];
  const float* Wc2   = (const float*)d_in[21];
  const float* bc2   = (const float*)d_in[22];
  float* out = (float*)d_out;

  const int N  = in_sizes[0] / 128;
  const int E  = in_sizes[1] / 2;
  const int ET = E + N;
  const int NB = (N + 127) >> 7;   // 128-node bins

  char* p = (char*)d_ws;
  auto take = [&](size_t bytes) -> void* {
    void* q = (void*)p;
    p += ((bytes + 255) & ~(size_t)255);
    return q;
  };
  // zero-initialized region (cursor + bincur + ovfcnt)
  int*   cursor = (int*)  take((size_t)N * 4);
  int*   bincur = (int*)  take((size_t)NB * 16 * 4);
  int*   ovfcnt = (int*)  take(256);
  size_t zbytes = (size_t)(p - (char*)d_ws);
  int*   count  = (int*)  take((size_t)N * 4);
  float* pool   = (float*)take(64 * 64 * 4);
  int*   ro     = (int*)  take((size_t)(N + 1) * 4);
  int*   bsum   = (int*)  take(1024);
  float* as1    = (float*)take((size_t)N * 16);
  float* ad1    = (float*)take((size_t)N * 16);
  float* as2    = (float*)take((size_t)N * 4);
  float* ad2    = (float*)take((size_t)N * 4);
  unsigned char*  xw1 = (unsigned char*) take((size_t)N * 256);
  unsigned short* h1  = (unsigned short*)take((size_t)N * 256 * 2);
  float* h2     = (float*)take((size_t)N * 64 * 4);
  int*   csr    = (int*)  take((size_t)ET * 4);
  int*   binbuf = (int*)  take((size_t)NB * CAPB * 4);
  int2*  ovfbuf = (int2*) take((size_t)OVFCAP * 8);
  unsigned short* B1p = (unsigned short*)take(32768 * 2);
  unsigned short* B2p = (unsigned short*)take(16384 * 2);
  unsigned short* xb  = (unsigned short*)h2;  // alias: xb dead before k_edge2 writes h2
  unsigned char*  xw2 = xw1;                  // alias: xw1 dead after k_edge1
  (void)n_in; (void)ws_size; (void)out_size;

  int zw = (int)(zbytes / 4);
  int zeroBlocks = (zw + 255) / 256;
  int n4 = N * 32;  // N*128/4
  int cvtBlocks = (n4 + 255) / 256;
  k_prep<<<dim3(zeroBlocks + cvtBlocks + 192), dim3(256), 0, stream>>>(
      (int*)d_ws, zw, zeroBlocks, x, xb, n4, W1, B1p, W2, B2p, cvtBlocks);
  k_binscat<<<dim3((ET + EPB - 1) / EPB), dim3(1024), 0, stream>>>(ei, bincur, binbuf,
                                                                   ovfcnt, ovfbuf, E, ET, NB);
  k_cnt<<<dim3(NB), dim3(256), 0, stream>>>(bincur, binbuf, count, N);
  k_cntovf<<<dim3(8), dim3(256), 0, stream>>>(ovfcnt, ovfbuf, count);
  int nb = (N + 255) / 256;
  k_scan1<<<dim3(nb), dim3(256), 0, stream>>>(count, ro, bsum, N);
  k_scan2<<<dim3(1), dim3(256), 0, stream>>>(bsum, nb);
  k_scan3<<<dim3(nb), dim3(256), 0, stream>>>(ro, bsum, N, ET);
  k_binsort<<<dim3(NB + 8), dim3(256), 0, stream>>>(bincur, binbuf, ro, csr,
                                                    ovfcnt, ovfbuf, cursor, N, NB);
  k_gemm1m<<<dim3((N + 63) / 64), dim3(256), 0, stream>>>(xb, (const bf16x8*)B1p,
                                                          asrc1, adst1, xw1, as1, ad1, N);
  k_edge1<<<dim3((N + 3) / 4), dim3(256), 0, stream>>>(ro, csr, xw1, as1, ad1,
                                                       bias1, bn1g, bn1b, bn1m, bn1v, h1, N);
  k_gemm2m<<<dim3((N + 63) / 64), dim3(256), 0, stream>>>(h1, (const bf16x8*)B2p,
                                                          asrc2, adst2, xw2, as2, ad2, N);
  k_edge2<<<dim3((N + 3) / 4), dim3(256), 0, stream>>>(ro, csr, xw2, as2, ad2,
                                                       bias2, bn2g, bn2b, bn2m, bn2v, h2, N);
  k_pool<<<dim3(64), dim3(256), 0, stream>>>(h2, batch, pool, N);
  k_final<<<dim3(64), dim3(64), 0, stream>>>(pool, Wc1, bc1, Wc2, bc2, out);
}